// Round 1
// baseline (25.515 us; speedup 1.0000x reference)
//
#include <hip/hip_runtime.h>
#include <math.h>

// Loss simplifies to: sum_i |sa_i - sb_i| / (N + 1e-8) / n
// where sa_i = #{j : pred[i] > pred[j]}, sb_i = #{j : gt[i] > gt[j]}.
// Exact integer pairwise rank-count computation, O(N^2) compares (134M @ N=8192).

constexpr int IB = 256;   // i's per block (= threads per block)
constexpr int JB = 1024;  // j's per block (LDS slice)

__global__ __launch_bounds__(IB) void rank_partial(
    const float* __restrict__ pred,
    const float* __restrict__ gt,
    int* __restrict__ sa,
    int* __restrict__ sb,
    int N)
{
    __shared__ float sp[JB];
    __shared__ float sg[JB];

    const int i  = blockIdx.x * IB + threadIdx.x;
    const int j0 = blockIdx.y * JB;

    // Cooperative load of the j-slice; pad out-of-range with +inf so that
    // strict-greater compares against padding are always false.
    for (int t = threadIdx.x; t < JB; t += IB) {
        int j = j0 + t;
        bool ok = (j < N);
        sp[t] = ok ? pred[j] : INFINITY;
        sg[t] = ok ? gt[j]   : INFINITY;
    }
    __syncthreads();

    if (i >= N) return;

    const float xi = pred[i];
    const float yi = gt[i];

    int ca = 0, cb = 0;
    const float4* sp4 = reinterpret_cast<const float4*>(sp);
    const float4* sg4 = reinterpret_cast<const float4*>(sg);
#pragma unroll 8
    for (int t = 0; t < JB / 4; ++t) {
        float4 p = sp4[t];
        float4 g = sg4[t];
        ca += (xi > p.x) + (xi > p.y) + (xi > p.z) + (xi > p.w);
        cb += (yi > g.x) + (yi > g.y) + (yi > g.z) + (yi > g.w);
    }

    atomicAdd(&sa[i], ca);
    atomicAdd(&sb[i], cb);
}

__global__ __launch_bounds__(1024) void reduce_final(
    const int* __restrict__ sa,
    const int* __restrict__ sb,
    float* __restrict__ out,
    int N, double inv)
{
    const int tid = threadIdx.x;
    int acc = 0;
    for (int i = tid; i < N; i += 1024) {
        int d = sa[i] - sb[i];
        acc += (d < 0) ? -d : d;
    }
    // wave64 reduce
    for (int off = 32; off > 0; off >>= 1)
        acc += __shfl_down(acc, off, 64);

    __shared__ int wsum[16];
    const int wid  = tid >> 6;
    const int lane = tid & 63;
    if (lane == 0) wsum[wid] = acc;
    __syncthreads();

    if (tid == 0) {
        int nw = (1024 + 63) / 64;
        int tot = 0;
        for (int w = 0; w < nw; ++w) tot += wsum[w];
        out[0] = (float)((double)tot * inv);
    }
}

extern "C" void kernel_launch(void* const* d_in, const int* in_sizes, int n_in,
                              void* d_out, int out_size, void* d_ws, size_t ws_size,
                              hipStream_t stream)
{
    const float* pred = (const float*)d_in[0];
    const float* gt   = (const float*)d_in[1];
    const int N = in_sizes[0];   // n == N per setup_inputs

    float* out = (float*)d_out;
    int* sa = (int*)d_ws;
    int* sb = sa + N;

    hipMemsetAsync(d_ws, 0, (size_t)2 * N * sizeof(int), stream);

    dim3 grid((N + IB - 1) / IB, (N + JB - 1) / JB);
    rank_partial<<<grid, IB, 0, stream>>>(pred, gt, sa, sb, N);

    const double inv = 1.0 / (((double)N + 1e-8) * (double)N);
    reduce_final<<<1, 1024, 0, stream>>>(sa, sb, out, N, inv);
}